// Round 1
// 1278.902 us; speedup vs baseline: 1.0189x; 1.0189x over previous
//
#include <hip/hip_runtime.h>

// Problem constants (from reference): B=2, C=32, N_IN=2^20, N_OUT=2^21.
constexpr int kNIn  = 1 << 20;
constexpr int kNOut = 1 << 21;
constexpr int kSlices = 2 * 32;              // B * C = 64
constexpr int kNXcd = 8;                     // MI355X: 8 XCDs, private 4 MiB L2 each
constexpr int kSlicesPerXcd = kSlices / kNXcd;           // 8
constexpr int kVec = 4;                      // float4 per thread
constexpr int kVecPerSlice = kNOut / kVec;   // 2^19
constexpr int kThreads = 256;
constexpr int kBlocksPerSlice = kVecPerSlice / kThreads; // 2048
constexpr int kTotalBlocks = kBlocksPerSlice * kSlices;  // 131072

typedef float  v4f __attribute__((ext_vector_type(4)));  // native vec for nt-store
typedef int    v4i __attribute__((ext_vector_type(4)));

// XCD-affine slice decomposition.
//
// Dispatch maps blockIdx round-robin over the 8 XCDs (bid % 8). We exploit
// that so each XCD owns 8 slices EXCLUSIVELY and walks them sequentially:
//   xcd   = bid % 8
//   l     = bid / 8          (in-dispatch-order position on this XCD)
//   slice = xcd*8 + l/2048   (2048 blocks per slice pass)
//   chunk = l % 2048         -> contiguous vec range within the slice
//
// Consequences:
//  * each input slice (4 MiB) is gathered by exactly ONE XCD -> fetched from
//    HBM once (256 MiB total), instead of once per XCD (2.05 GB, the
//    measured FETCH_SIZE of the previous version).
//  * the ~256 resident blocks per XCD sit in a contiguous l-window, i.e.
//    inside one slice pass -> gather working set = one 4 MiB window = the
//    XCD's entire private L2. idx reads are nontemporal and the output
//    stream is nt-stored so neither evicts the gather window.
__global__ __launch_bounds__(256)
void SampleParticles_36653250904489_kernel(const float* __restrict__ in,
                                           const int*   __restrict__ pidx,
                                           float*       __restrict__ out) {
    const int bid   = blockIdx.x;
    const int xcd   = bid & (kNXcd - 1);
    const int l     = bid >> 3;                            // per-XCD order
    const int slice = xcd * kSlicesPerXcd + (l >> 11);     // l / kBlocksPerSlice
    const int chunk = l & (kBlocksPerSlice - 1);
    const int vec_i = chunk * kThreads + (int)threadIdx.x;

    // Index load: coalesced int4, streaming (read once per slice pass per
    // XCD, L3-resident at 8 MiB) -> nontemporal so it doesn't pollute the
    // L2 gather window.
    const v4i p = __builtin_nontemporal_load(((const v4i* __restrict__)pidx) + vec_i);

    // Gather within this slice's 4 MiB window (exactly one XCD L2).
    const float* __restrict__ base = in + (size_t)slice * kNIn;
    v4f v;
    v.x = base[p.x];
    v.y = base[p.y];
    v.z = base[p.z];
    v.w = base[p.w];

    // Streaming store: never re-read; nt keeps the 512 MiB write stream from
    // evicting the gather working set in L2.
    v4f* dst = (v4f*)(out + (size_t)slice * kNOut) + vec_i;
    __builtin_nontemporal_store(v, dst);
}

extern "C" void kernel_launch(void* const* d_in, const int* in_sizes, int n_in,
                              void* d_out, int out_size, void* d_ws, size_t ws_size,
                              hipStream_t stream) {
    const float* in   = (const float*)d_in[0];
    const int*   pidx = (const int*)d_in[1];
    float*       out  = (float*)d_out;

    SampleParticles_36653250904489_kernel<<<kTotalBlocks, kThreads, 0, stream>>>(in, pidx, out);
}

// Round 2
// 783.718 us; speedup vs baseline: 1.6626x; 1.6318x over previous
//
#include <hip/hip_runtime.h>

// Problem constants (from reference): B=2, C=32, N_IN=2^20, N_OUT=2^21.
constexpr int kNIn    = 1 << 20;
constexpr int kNOut   = 1 << 21;
constexpr int kSlices = 64;                  // B * C
constexpr int kThreads = 256;

typedef float  v4f __attribute__((ext_vector_type(4)));
typedef int    v4i __attribute__((ext_vector_type(4)));

// ---------------------------------------------------------------------------
// Pass 1: transpose in[64][N_IN] -> trans[N_IN][64]  (ws workspace).
// Tile = 64 slices x 64 particles through LDS, both global sides coalesced.
// LDS stride 65 floats: word%32 analysis gives exactly 2-way aliasing on both
// phases, which is free on CDNA4 (32 banks, 64 lanes).
// ---------------------------------------------------------------------------
__global__ __launch_bounds__(256)
void SampleParticles_transpose_kernel(const float* __restrict__ in,
                                      float* __restrict__ trans) {
    __shared__ float tile[64][65];
    const int p0 = blockIdx.x * 64;          // particle tile base
    const int t  = threadIdx.x;
    const int a  = t >> 4;                   // 0..15
    const int b4 = (t & 15) * 4;             // 0..60 (float offset)

    #pragma unroll
    for (int it = 0; it < 4; ++it) {
        const int s = a + it * 16;           // slice row
        const v4f v = __builtin_nontemporal_load(
            (const v4f*)(in + (size_t)s * kNIn + p0 + b4));
        tile[s][b4 + 0] = v.x;
        tile[s][b4 + 1] = v.y;
        tile[s][b4 + 2] = v.z;
        tile[s][b4 + 3] = v.w;
    }
    __syncthreads();
    #pragma unroll
    for (int it = 0; it < 4; ++it) {
        const int r = a + it * 16;           // particle row
        v4f v;
        v.x = tile[b4 + 0][r];
        v.y = tile[b4 + 1][r];
        v.z = tile[b4 + 2][r];
        v.w = tile[b4 + 3][r];
        // trans row (p0+r) is 256B, written as 16 consecutive 16B chunks by
        // the 16-lane group -> fully coalesced (1 KiB contiguous per wave).
        *(v4f*)(trans + (size_t)(p0 + r) * kSlices + b4) = v;
    }
}

// ---------------------------------------------------------------------------
// Pass 2: out[s][i] = trans[pidx[i]][s].
// Block handles 64 consecutive output particles. The gather is now ROW
// granular: each random row is 256B aligned-contiguous = 4 cache lines, all
// bytes used (vs 4 useful bytes / 64B line in the direct version -- that 16x
// line-utilization gap is what capped R1 at 783us / 22% HBM).
// ---------------------------------------------------------------------------
__global__ __launch_bounds__(256)
void SampleParticles_gather_kernel(const float* __restrict__ trans,
                                   const int*   __restrict__ pidx,
                                   float*       __restrict__ out) {
    __shared__ int   idx[64];
    __shared__ float tile[64][65];           // [i_local][slice]
    const int i0 = blockIdx.x * 64;          // output particle tile base
    const int t  = threadIdx.x;
    if (t < 64) idx[t] = pidx[i0 + t];
    __syncthreads();

    const int a  = t >> 4;                   // 0..15
    const int b4 = (t & 15) * 4;             // 0..60

    #pragma unroll
    for (int it = 0; it < 4; ++it) {
        const int il = a + it * 16;          // local output particle
        const int p  = idx[il];              // broadcast within 16-lane group
        const v4f v = *(const v4f*)(trans + (size_t)p * kSlices + b4);
        tile[il][b4 + 0] = v.x;
        tile[il][b4 + 1] = v.y;
        tile[il][b4 + 2] = v.z;
        tile[il][b4 + 3] = v.w;
    }
    __syncthreads();
    #pragma unroll
    for (int it = 0; it < 4; ++it) {
        const int s = a + it * 16;           // slice
        v4f v;
        v.x = tile[b4 + 0][s];
        v.y = tile[b4 + 1][s];
        v.z = tile[b4 + 2][s];
        v.w = tile[b4 + 3][s];
        // out[s][i0 + b4 .. +3]: 16-lane group writes 256B contiguous.
        __builtin_nontemporal_store(
            v, (v4f*)(out + (size_t)s * kNOut + i0 + b4));
    }
}

// ---------------------------------------------------------------------------
// Fallback (R1 kernel): direct XCD-affine gather, used only if the workspace
// cannot hold the 256 MiB transposed feature array.
// ---------------------------------------------------------------------------
constexpr int kNXcd = 8;
constexpr int kSlicesPerXcd = kSlices / kNXcd;
constexpr int kVecPerSlice = kNOut / 4;
constexpr int kBlocksPerSlice = kVecPerSlice / kThreads; // 2048
constexpr int kTotalBlocksDirect = kBlocksPerSlice * kSlices;

__global__ __launch_bounds__(256)
void SampleParticles_direct_kernel(const float* __restrict__ in,
                                   const int*   __restrict__ pidx,
                                   float*       __restrict__ out) {
    const int bid   = blockIdx.x;
    const int xcd   = bid & (kNXcd - 1);
    const int l     = bid >> 3;
    const int slice = xcd * kSlicesPerXcd + (l >> 11);
    const int chunk = l & (kBlocksPerSlice - 1);
    const int vec_i = chunk * kThreads + (int)threadIdx.x;

    const v4i p = __builtin_nontemporal_load(((const v4i*)pidx) + vec_i);
    const float* __restrict__ base = in + (size_t)slice * kNIn;
    v4f v;
    v.x = base[p.x];
    v.y = base[p.y];
    v.z = base[p.z];
    v.w = base[p.w];
    v4f* dst = (v4f*)(out + (size_t)slice * kNOut) + vec_i;
    __builtin_nontemporal_store(v, dst);
}

extern "C" void kernel_launch(void* const* d_in, const int* in_sizes, int n_in,
                              void* d_out, int out_size, void* d_ws, size_t ws_size,
                              hipStream_t stream) {
    const float* in   = (const float*)d_in[0];
    const int*   pidx = (const int*)d_in[1];
    float*       out  = (float*)d_out;

    const size_t kTransBytes = (size_t)kNIn * kSlices * sizeof(float); // 256 MiB
    if (d_ws != nullptr && ws_size >= kTransBytes) {
        float* trans = (float*)d_ws;
        SampleParticles_transpose_kernel<<<kNIn / 64, kThreads, 0, stream>>>(in, trans);
        SampleParticles_gather_kernel<<<kNOut / 64, kThreads, 0, stream>>>(trans, pidx, out);
    } else {
        SampleParticles_direct_kernel<<<kTotalBlocksDirect, kThreads, 0, stream>>>(in, pidx, out);
    }
}